// Round 1
// 289.766 us; speedup vs baseline: 1.0069x; 1.0069x over previous
//
#include <hip/hip_runtime.h>
#include <cstdint>
#include <cstddef>

// All external tensors are FP32 (per reference). Internals use bf16 for MFMA.
typedef unsigned short u16;
typedef __attribute__((ext_vector_type(4))) float f32x4;
typedef __attribute__((ext_vector_type(8))) __bf16 bf16x8;
typedef __attribute__((ext_vector_type(4))) __bf16 bf16x4;
typedef __attribute__((ext_vector_type(8))) unsigned short u16x8;

#define DEV static __device__ __forceinline__

#if __has_builtin(__builtin_amdgcn_exp2f)
#define EXP2(x) __builtin_amdgcn_exp2f(x)
#else
#define EXP2(x) exp2f(x)
#endif

DEV float bf2f(u16 v) { return __uint_as_float(((unsigned)v) << 16); }
DEV u16 f2bf(float f) {
  unsigned u = __float_as_uint(f);
  return (u16)((u + 0x7FFFu + ((u >> 16) & 1u)) >> 16);
}

DEV void gl_lds16(const void* g, void* l) {
  __builtin_amdgcn_global_load_lds((const __attribute__((address_space(1))) void*)g,
                                   (__attribute__((address_space(3))) void*)l, 16, 0, 0);
}

// ---------------------------------------------------------------------------
// 64x64 tiled transpose + fp32->bf16 cast: out[c][r] = bf16(in[r][c]).
__global__ __launch_bounds__(256) void transpose64(const float* __restrict__ in,
                                                   u16* __restrict__ out, int incols) {
  __shared__ __attribute__((aligned(16))) u16 t[64 * 72];
  const int r0 = blockIdx.x * 64, c0 = blockIdx.y * 64, tid = threadIdx.x;
#pragma unroll
  for (int i = 0; i < 2; i++) {
    int c = i * 256 + tid;
    int row = c >> 3, cc = c & 7;
    const float* src = &in[(size_t)(r0 + row) * incols + c0 + cc * 8];
    f32x4 v0 = *(const f32x4*)src;
    f32x4 v1 = *(const f32x4*)(src + 4);
    u16x8 o;
#pragma unroll
    for (int j = 0; j < 4; j++) { o[j] = f2bf(v0[j]); o[4 + j] = f2bf(v1[j]); }
    *(u16x8*)&t[row * 72 + cc * 8] = o;
  }
  __syncthreads();
#pragma unroll
  for (int i = 0; i < 2; i++) {
    int c = i * 256 + tid;
    int d = c >> 3, nc = c & 7;
    u16x8 o;
#pragma unroll
    for (int j = 0; j < 8; j++) o[j] = t[(nc * 8 + j) * 72 + d];
    *(u16x8*)&out[(size_t)(c0 + d) * 1024 + r0 + nc * 8] = o;
  }
}

// ---------------------------------------------------------------------------
// LayerNorm over DIM=1024 (fp32 in, bf16 out), one block per row.
__global__ __launch_bounds__(256) void ln_x(const float* __restrict__ x,
                                            const float* __restrict__ sc,
                                            const float* __restrict__ bi,
                                            u16* __restrict__ xn) {
  __shared__ float red[8];
  const int row = blockIdx.x, tid = threadIdx.x;
  const int w = tid >> 6;
  f32x4 f = *(const f32x4*)&x[(size_t)row * 1024 + tid * 4];
  float s = f[0] + f[1] + f[2] + f[3];
  float q = f[0] * f[0] + f[1] * f[1] + f[2] * f[2] + f[3] * f[3];
#pragma unroll
  for (int off = 1; off < 64; off <<= 1) {
    s += __shfl_xor(s, off);
    q += __shfl_xor(q, off);
  }
  if ((tid & 63) == 0) { red[w] = s; red[4 + w] = q; }
  __syncthreads();
  float S = red[0] + red[1] + red[2] + red[3];
  float Q = red[4] + red[5] + red[6] + red[7];
  float mu = S * (1.0f / 1024.0f);
  float var = Q * (1.0f / 1024.0f) - mu * mu;
  float rs = rsqrtf(var + 1e-6f);
  f32x4 scv = *(const f32x4*)&sc[tid * 4];
  f32x4 biv = *(const f32x4*)&bi[tid * 4];
  u16* o = xn + (size_t)row * 1024 + tid * 4;
#pragma unroll
  for (int j = 0; j < 4; j++) o[j] = f2bf((f[j] - mu) * rs * scv[j] + biv[j]);
}

// ---------------------------------------------------------------------------
// C[M][N] = A[M][K] * Bt[N][K]^T, bf16 in; out bf16 or fp32 (F32OUT).
// 128x128 tile, BK=64 (half the barriers of BK=32), XOR-swizzled LDS
// (logical 16B chunk c of row r lives at slot c^(r&7)) -> <=2-way conflicts.
template <bool F32OUT>
__global__ __launch_bounds__(256) void gemm_bt(const u16* __restrict__ A,
                                               const u16* __restrict__ Bt,
                                               void* __restrict__ Cp,
                                               int M, int N, int K) {
  __shared__ __attribute__((aligned(16))) u16 Als[128 * 64];
  __shared__ __attribute__((aligned(16))) u16 Bls[128 * 64];
  const int tid = threadIdx.x;
  const int w = tid >> 6, lane = tid & 63, ln = lane & 15, quad = lane >> 4;
  const int m0 = blockIdx.y * 128, n0 = blockIdx.x * 128;
  const int moff = (w & 1) * 64, noff = (w >> 1) * 64;
  const f32x4 fzero = {0.f, 0.f, 0.f, 0.f};
  f32x4 acc[4][4];
#pragma unroll
  for (int i = 0; i < 4; i++)
#pragma unroll
    for (int j = 0; j < 4; j++) acc[i][j] = fzero;

  // staging source bases: 4 chunks each for A and B per thread
  const u16* aS[4];
  const u16* bS[4];
#pragma unroll
  for (int i = 0; i < 4; i++) {
    int s = i * 256 + tid;
    int row = s >> 3, cs = (s & 7) ^ (row & 7);
    aS[i] = A + (size_t)(m0 + row) * K + cs * 8;
    bS[i] = Bt + (size_t)(n0 + row) * K + cs * 8;
  }

  for (int k0 = 0; k0 < K; k0 += 64) {
    __syncthreads();
#pragma unroll
    for (int i = 0; i < 4; i++) {
      int s = i * 256 + tid;
      gl_lds16(aS[i] + k0, &Als[s * 8]);
      gl_lds16(bS[i] + k0, &Bls[s * 8]);
    }
    __syncthreads();
#pragma unroll
    for (int kk = 0; kk < 2; kk++) {
      bf16x8 af[4], bfv[4];
#pragma unroll
      for (int mi = 0; mi < 4; mi++)
        af[mi] = *(const bf16x8*)
            &Als[(moff + mi * 16 + ln) * 64 + (((kk * 4 + quad) ^ (ln & 7)) * 8)];
#pragma unroll
      for (int ni = 0; ni < 4; ni++)
        bfv[ni] = *(const bf16x8*)
            &Bls[(noff + ni * 16 + ln) * 64 + (((kk * 4 + quad) ^ (ln & 7)) * 8)];
#pragma unroll
      for (int mi = 0; mi < 4; mi++)
#pragma unroll
        for (int ni = 0; ni < 4; ni++)
          acc[mi][ni] = __builtin_amdgcn_mfma_f32_16x16x32_bf16(af[mi], bfv[ni],
                                                                acc[mi][ni], 0, 0, 0);
    }
  }
#pragma unroll
  for (int mi = 0; mi < 4; mi++)
#pragma unroll
    for (int ni = 0; ni < 4; ni++)
#pragma unroll
      for (int r = 0; r < 4; r++) {
        size_t m = m0 + moff + mi * 16 + quad * 4 + r;
        size_t n = n0 + noff + ni * 16 + ln;
        if (F32OUT)
          ((float*)Cp)[m * N + n] = acc[mi][ni][r];
        else
          ((u16*)Cp)[m * N + n] = f2bf(acc[mi][ni][r]);
      }
}

// ---------------------------------------------------------------------------
// Per-head LN of q and k slices of qkv[8192][1536] (bf16); fp32 params.
// Q pre-scaled by 0.125*log2(e): scores directly in exp2 domain (fixed-max
// softmax is safe: LN'd q,k => |score| <= ~11.5).
__global__ __launch_bounds__(256) void qk_ln(const u16* __restrict__ qkv,
                                             const float* __restrict__ qs,
                                             const float* __restrict__ qb,
                                             const float* __restrict__ ks,
                                             const float* __restrict__ kb,
                                             u16* __restrict__ Q,
                                             u16* __restrict__ Kb) {
  const float SCL = 0.18033688011112042f;  // 0.125 * log2(e)
  const int m = blockIdx.x;
  const int b = m >> 11, n = m & 2047;
  const int tid = threadIdx.x, w = tid >> 6, lane = tid & 63;
  const u16* rowp = qkv + (size_t)m * 1536;
  const float qsc = qs[lane], qbi = qb[lane];
  const float ksc = ks[lane], kbi = kb[lane];
#pragma unroll
  for (int i = 0; i < 4; i++) {
    int h = w * 4 + i;
    float v = bf2f(rowp[h * 64 + lane]);
    float s = v, q2 = v * v;
#pragma unroll
    for (int off = 1; off < 64; off <<= 1) {
      s += __shfl_xor(s, off);
      q2 += __shfl_xor(q2, off);
    }
    float mu = s * (1.0f / 64.0f);
    float var = q2 * (1.0f / 64.0f) - mu * mu;
    float y = ((v - mu) * rsqrtf(var + 1e-6f) * qsc + qbi) * SCL;
    Q[((size_t)(b * 16 + h) * 2048 + n) * 64 + lane] = f2bf(y);
  }
  {
    int g = w;
    float v = bf2f(rowp[1024 + g * 64 + lane]);
    float s = v, q2 = v * v;
#pragma unroll
    for (int off = 1; off < 64; off <<= 1) {
      s += __shfl_xor(s, off);
      q2 += __shfl_xor(q2, off);
    }
    float mu = s * (1.0f / 64.0f);
    float var = q2 * (1.0f / 64.0f) - mu * mu;
    float y = (v - mu) * rsqrtf(var + 1e-6f) * ksc + kbi;
    Kb[((size_t)(b * 4 + g) * 2048 + n) * 64 + lane] = f2bf(y);
  }
}

// ---------------------------------------------------------------------------
// V transpose: qkv v-slice -> Vt [b][g][64][2048]. grid = (32, 16).
__global__ __launch_bounds__(256) void vtrans(const u16* __restrict__ qkv,
                                              u16* __restrict__ Vt) {
  __shared__ __attribute__((aligned(16))) u16 t[64 * 72];
  const int n0 = blockIdx.x * 64;
  const int bg = blockIdx.y;
  const int b = bg >> 2, g = bg & 3;
  const int tid = threadIdx.x;
  const u16* src = qkv + (size_t)(b * 2048 + n0) * 1536 + 1280 + g * 64;
#pragma unroll
  for (int i = 0; i < 2; i++) {
    int c = i * 256 + tid;
    int row = c >> 3, cc = c & 7;
    *(f32x4*)&t[row * 72 + cc * 8] = *(const f32x4*)&src[(size_t)row * 1536 + cc * 8];
  }
  __syncthreads();
  u16* dst = Vt + (size_t)bg * 64 * 2048 + n0;
#pragma unroll
  for (int i = 0; i < 2; i++) {
    int c = i * 256 + tid;
    int d = c >> 3, nc = c & 7;
    u16x8 o;
#pragma unroll
    for (int j = 0; j < 8; j++) o[j] = t[(nc * 8 + j) * 72 + d];
    *(u16x8*)&dst[(size_t)d * 2048 + nc * 8] = o;
  }
}

// ---------------------------------------------------------------------------
// Flash attention, transposed-S, fixed-max softmax, KT=64 keys/iter.
// grid = (16, 64), block = 256 (4 waves x 32 q-rows).
//
// Round-1 rewrite:
//  * P never touches LDS. With transposed S (sacc = mfma(K, Q)), lane
//    (ln,quad) holds S^T[key=ni*16+quad*4+r][m=ln] — same column m=ln that
//    the PV B-operand needs at this lane. We pick the PV MFMA's virtual-key
//    order kappa=quad*8+j |-> physical key 32*kc + (j>=4)*16 + quad*4 + (j&3),
//    so the B-fragment is just bf16(sacc[mi][2kc]) ++ bf16(sacc[mi][2kc+1])
//    (lane-local registers). V's A-fragment uses the SAME physical-key order:
//    two swizzled ds_read_b64 per (ni,kc) instead of one b128.
//    Removes 8x 4-way-conflicted ds_write_b64 + 4x ds_read_b128 per wave/kt
//    (the 4.2M SQ_LDS_BANK_CONFLICT source) and the 16 KB Pls.
//  * K/V double-buffered in the freed LDS (2x8KB + 2x8KB = 32 KB total):
//    ONE barrier per kt, next tile's global_load_lds issued before compute
//    so staging latency hides under QK^T/softmax/PV (T3 2-phase shape).
// __launch_bounds__(256,4) caps VGPR at 128 -> keeps 4 blocks x 4 waves /CU.
__global__ __launch_bounds__(256, 4) void attn(const u16* __restrict__ Q,
                                               const u16* __restrict__ Kb,
                                               const u16* __restrict__ Vt,
                                               u16* __restrict__ Out) {
  __shared__ __attribute__((aligned(16))) u16 Kls0[64 * 64];
  __shared__ __attribute__((aligned(16))) u16 Kls1[64 * 64];
  __shared__ __attribute__((aligned(16))) u16 Vls0[64 * 64];
  __shared__ __attribute__((aligned(16))) u16 Vls1[64 * 64];
  const int qt = blockIdx.x;
  const int bh = blockIdx.y;
  const int b = bh >> 4, h = bh & 15, g = h >> 2;
  const int tid = threadIdx.x, w = tid >> 6, lane = tid & 63;
  const int ln = lane & 15, quad = lane >> 4;
  const u16* Qg = Q + ((size_t)(b * 16 + h) * 2048 + qt * 128 + w * 32) * 64;
  const u16* Kg = Kb + (size_t)(b * 4 + g) * 2048 * 64;
  const u16* Vg = Vt + (size_t)(b * 4 + g) * 64 * 2048;
  const f32x4 fzero = {0.f, 0.f, 0.f, 0.f};

  // Q fragments (B-operand): rows m = mi*16+ln, k(d) = ks2*32 + quad*8
  bf16x8 qf[2][2];
#pragma unroll
  for (int mi = 0; mi < 2; mi++)
#pragma unroll
    for (int ks2 = 0; ks2 < 2; ks2++)
      qf[mi][ks2] = *(const bf16x8*)&Qg[(size_t)(mi * 16 + ln) * 64 + ks2 * 32 + quad * 8];

  f32x4 oacc[4][2];  // [ni(d-tile)][mi(m-tile)]
#pragma unroll
  for (int ni = 0; ni < 4; ni++)
#pragma unroll
    for (int mi = 0; mi < 2; mi++) oacc[ni][mi] = fzero;
  float lsum[2] = {0.f, 0.f};

  // staging geometry (constant per thread)
  const int sk0 = tid, sk1 = 256 + tid;
  const int krow0 = sk0 >> 3, kcs0 = (sk0 & 7) ^ (krow0 & 7);
  const int krow1 = sk1 >> 3, kcs1 = (sk1 & 7) ^ (krow1 & 7);

  auto STAGE = [&](int kt, u16* Kd, u16* Vd) {
    gl_lds16(Kg + (size_t)(kt * 64 + krow0) * 64 + kcs0 * 8, &Kd[sk0 * 8]);
    gl_lds16(Kg + (size_t)(kt * 64 + krow1) * 64 + kcs1 * 8, &Kd[sk1 * 8]);
    gl_lds16(Vg + (size_t)krow0 * 2048 + kt * 64 + kcs0 * 8, &Vd[sk0 * 8]);
    gl_lds16(Vg + (size_t)krow1 * 2048 + kt * 64 + kcs1 * 8, &Vd[sk1 * 8]);
  };

  auto BODY = [&](int kt, const u16* K_, const u16* V_, u16* Kn, u16* Vn) {
    if (kt + 1 < 32) STAGE(kt + 1, Kn, Vn);  // prefetch, in flight during compute

    // S^T: sacc[mi][ni][r] = S[key=ni*16+quad*4+r][m=mi*16+ln] (exp2 domain)
    f32x4 sacc[2][4];
#pragma unroll
    for (int ni = 0; ni < 4; ni++) {
      const int krow = ni * 16 + ln;
      bf16x8 kf0 = *(const bf16x8*)&K_[krow * 64 + ((quad ^ (ln & 7)) * 8)];
      bf16x8 kf1 = *(const bf16x8*)&K_[krow * 64 + (((4 + quad) ^ (ln & 7)) * 8)];
#pragma unroll
      for (int mi = 0; mi < 2; mi++) {
        f32x4 tt = __builtin_amdgcn_mfma_f32_16x16x32_bf16(kf0, qf[mi][0], fzero, 0, 0, 0);
        sacc[mi][ni] = __builtin_amdgcn_mfma_f32_16x16x32_bf16(kf1, qf[mi][1], tt, 0, 0, 0);
      }
    }

    // fixed-max softmax: p = exp2(s), packed straight into PV B-fragments.
    // pfa[mi][kc] element j: j<4 -> exp2(sacc[mi][2kc][j]); j>=4 -> exp2(sacc[mi][2kc+1][j-4])
    bf16x8 pfa[2][2];
#pragma unroll
    for (int mi = 0; mi < 2; mi++) {
      float ls = 0.f;
#pragma unroll
      for (int ni = 0; ni < 4; ni++) {
        float p0 = EXP2(sacc[mi][ni][0]);
        float p1 = EXP2(sacc[mi][ni][1]);
        float p2 = EXP2(sacc[mi][ni][2]);
        float p3 = EXP2(sacc[mi][ni][3]);
        ls += (p0 + p1) + (p2 + p3);
        const int e = (ni & 1) * 4;
        pfa[mi][ni >> 1][e + 0] = (__bf16)p0;
        pfa[mi][ni >> 1][e + 1] = (__bf16)p1;
        pfa[mi][ni >> 1][e + 2] = (__bf16)p2;
        pfa[mi][ni >> 1][e + 3] = (__bf16)p3;
      }
      ls += __shfl_xor(ls, 16);
      ls += __shfl_xor(ls, 32);
      lsum[mi] += ls;
    }

    // O^T += Vt * P^T. Virtual key kappa=quad*8+j; physical key
    // 32kc + (j>=4)*16 + quad*4 + (j&3). V A-frag = two ds_read_b64.
#pragma unroll
    for (int kc = 0; kc < 2; kc++) {
#pragma unroll
      for (int ni = 0; ni < 4; ni++) {
        const int base = (ni * 16 + ln) * 64 + (quad & 1) * 4;
        bf16x4 va = *(const bf16x4*)&V_[base + (((4 * kc + (quad >> 1)) ^ (ln & 7)) * 8)];
        bf16x4 vb = *(const bf16x4*)&V_[base + (((4 * kc + 2 + (quad >> 1)) ^ (ln & 7)) * 8)];
        bf16x8 vf;
        vf[0] = va[0]; vf[1] = va[1]; vf[2] = va[2]; vf[3] = va[3];
        vf[4] = vb[0]; vf[5] = vb[1]; vf[6] = vb[2]; vf[7] = vb[3];
#pragma unroll
        for (int mi = 0; mi < 2; mi++)
          oacc[ni][mi] = __builtin_amdgcn_mfma_f32_16x16x32_bf16(vf, pfa[mi][kc],
                                                                 oacc[ni][mi], 0, 0, 0);
      }
    }
    __syncthreads();  // drains prefetch vmcnt; all waves done reading K_/V_
  };

  STAGE(0, Kls0, Vls0);
  __syncthreads();
  for (int kt = 0; kt < 32; kt += 2) {
    BODY(kt, Kls0, Vls0, Kls1, Vls1);
    BODY(kt + 1, Kls1, Vls1, Kls0, Vls0);
  }

  // epilogue: O[m][d] = O^T / lsum; row n = qt*128 + w*32 + mi*16 + ln
#pragma unroll
  for (int mi = 0; mi < 2; mi++) {
    float inv = 1.0f / lsum[mi];
    u16* Og = Out + ((size_t)b * 2048 + qt * 128 + w * 32 + mi * 16 + ln) * 1024 + h * 64;
#pragma unroll
    for (int ni = 0; ni < 4; ni++) {
      bf16x4 ov = {(__bf16)(oacc[ni][mi][0] * inv), (__bf16)(oacc[ni][mi][1] * inv),
                   (__bf16)(oacc[ni][mi][2] * inv), (__bf16)(oacc[ni][mi][3] * inv)};
      *(bf16x4*)&Og[ni * 16 + quad * 4] = ov;
    }
  }
}

// ---------------------------------------------------------------------------
extern "C" void kernel_launch(void* const* d_in, const int* in_sizes, int n_in,
                              void* d_out, int out_size, void* d_ws, size_t ws_size,
                              hipStream_t stream) {
  const float* x    = (const float*)d_in[0];
  const float* lns  = (const float*)d_in[1];
  const float* lnb  = (const float*)d_in[2];
  const float* Wq   = (const float*)d_in[3];
  const float* Wkv  = (const float*)d_in[4];
  const float* qns  = (const float*)d_in[5];
  const float* qnb  = (const float*)d_in[6];
  const float* kns  = (const float*)d_in[7];
  const float* knb  = (const float*)d_in[8];
  const float* Wout = (const float*)d_in[9];
  float* out = (float*)d_out;
  char* ws = (char*)d_ws;

  const size_t o_xn  = 0;                 // 16 MB: xn (bf16), later Qbuf
  const size_t o_qkv = 16777216;          // 24 MB: qkv (bf16), later attn_out
  const size_t o_bt  = o_qkv + 25165824;  // 3 MB: W^T (bf16), reused for Wout^T
  const size_t o_k   = o_bt + 3145728;    // 4 MB: Kbuf
  const size_t o_vt  = o_k + 4194304;     // 4 MB: Vtbuf
  u16* xn   = (u16*)(ws + o_xn);
  u16* qkv  = (u16*)(ws + o_qkv);
  u16* bt   = (u16*)(ws + o_bt);
  u16* Kbuf = (u16*)(ws + o_k);
  u16* Vtb  = (u16*)(ws + o_vt);
  u16* Qbuf = xn;    // xn dead after GEMM1
  u16* aout = qkv;   // qkv dead after qk_ln/vtrans

  transpose64<<<dim3(16, 16), 256, 0, stream>>>(Wq, bt, 1024);
  transpose64<<<dim3(16, 8), 256, 0, stream>>>(Wkv, bt + 1024 * 1024, 512);
  ln_x<<<8192, 256, 0, stream>>>(x, lns, lnb, xn);
  gemm_bt<false><<<dim3(12, 64), 256, 0, stream>>>(xn, bt, qkv, 8192, 1536, 1024);
  transpose64<<<dim3(16, 16), 256, 0, stream>>>(Wout, bt, 1024);
  qk_ln<<<8192, 256, 0, stream>>>(qkv, qns, qnb, kns, knb, Qbuf, Kbuf);
  vtrans<<<dim3(32, 16), 256, 0, stream>>>(qkv, Vtb);
  attn<<<dim3(16, 64), 256, 0, stream>>>(Qbuf, Kbuf, Vtb, aout);
  gemm_bt<true><<<dim3(8, 64), 256, 0, stream>>>(aout, bt, out, 8192, 1024, 1024);

  (void)in_sizes; (void)n_in; (void)out_size; (void)ws_size;
}

// Round 2
// 276.399 us; speedup vs baseline: 1.0556x; 1.0484x over previous
//
#include <hip/hip_runtime.h>
#include <cstdint>
#include <cstddef>

// All external tensors are FP32 (per reference). Internals use bf16 for MFMA.
typedef unsigned short u16;
typedef __attribute__((ext_vector_type(4))) float f32x4;
typedef __attribute__((ext_vector_type(8))) __bf16 bf16x8;
typedef __attribute__((ext_vector_type(4))) __bf16 bf16x4;
typedef __attribute__((ext_vector_type(8))) unsigned short u16x8;
typedef __attribute__((ext_vector_type(4))) unsigned short u16x4;

#define DEV static __device__ __forceinline__

#if __has_builtin(__builtin_amdgcn_exp2f)
#define EXP2(x) __builtin_amdgcn_exp2f(x)
#else
#define EXP2(x) exp2f(x)
#endif

DEV float bf2f(u16 v) { return __uint_as_float(((unsigned)v) << 16); }
DEV u16 f2bf(float f) {
  unsigned u = __float_as_uint(f);
  return (u16)((u + 0x7FFFu + ((u >> 16) & 1u)) >> 16);
}

DEV void gl_lds16(const void* g, void* l) {
  __builtin_amdgcn_global_load_lds((const __attribute__((address_space(1))) void*)g,
                                   (__attribute__((address_space(3))) void*)l, 16, 0, 0);
}

// ---------------------------------------------------------------------------
// 64x64 tiled transpose + fp32->bf16 cast: out[c][r] = bf16(in[r][c]).
__global__ __launch_bounds__(256) void transpose64(const float* __restrict__ in,
                                                   u16* __restrict__ out, int incols) {
  __shared__ __attribute__((aligned(16))) u16 t[64 * 72];
  const int r0 = blockIdx.x * 64, c0 = blockIdx.y * 64, tid = threadIdx.x;
#pragma unroll
  for (int i = 0; i < 2; i++) {
    int c = i * 256 + tid;
    int row = c >> 3, cc = c & 7;
    const float* src = &in[(size_t)(r0 + row) * incols + c0 + cc * 8];
    f32x4 v0 = *(const f32x4*)src;
    f32x4 v1 = *(const f32x4*)(src + 4);
    u16x8 o;
#pragma unroll
    for (int j = 0; j < 4; j++) { o[j] = f2bf(v0[j]); o[4 + j] = f2bf(v1[j]); }
    *(u16x8*)&t[row * 72 + cc * 8] = o;
  }
  __syncthreads();
#pragma unroll
  for (int i = 0; i < 2; i++) {
    int c = i * 256 + tid;
    int d = c >> 3, nc = c & 7;
    u16x8 o;
#pragma unroll
    for (int j = 0; j < 8; j++) o[j] = t[(nc * 8 + j) * 72 + d];
    *(u16x8*)&out[(size_t)(c0 + d) * 1024 + r0 + nc * 8] = o;
  }
}

// ---------------------------------------------------------------------------
// LayerNorm over DIM=1024 (fp32 in, bf16 out), one block per row.
__global__ __launch_bounds__(256) void ln_x(const float* __restrict__ x,
                                            const float* __restrict__ sc,
                                            const float* __restrict__ bi,
                                            u16* __restrict__ xn) {
  __shared__ float red[8];
  const int row = blockIdx.x, tid = threadIdx.x;
  const int w = tid >> 6;
  f32x4 f = *(const f32x4*)&x[(size_t)row * 1024 + tid * 4];
  float s = f[0] + f[1] + f[2] + f[3];
  float q = f[0] * f[0] + f[1] * f[1] + f[2] * f[2] + f[3] * f[3];
#pragma unroll
  for (int off = 1; off < 64; off <<= 1) {
    s += __shfl_xor(s, off);
    q += __shfl_xor(q, off);
  }
  if ((tid & 63) == 0) { red[w] = s; red[4 + w] = q; }
  __syncthreads();
  float S = red[0] + red[1] + red[2] + red[3];
  float Q = red[4] + red[5] + red[6] + red[7];
  float mu = S * (1.0f / 1024.0f);
  float var = Q * (1.0f / 1024.0f) - mu * mu;
  float rs = rsqrtf(var + 1e-6f);
  f32x4 scv = *(const f32x4*)&sc[tid * 4];
  f32x4 biv = *(const f32x4*)&bi[tid * 4];
  u16* o = xn + (size_t)row * 1024 + tid * 4;
#pragma unroll
  for (int j = 0; j < 4; j++) o[j] = f2bf((f[j] - mu) * rs * scv[j] + biv[j]);
}

// ---------------------------------------------------------------------------
// C[M][N] = A[M][K] * Bt[N][K]^T, bf16 in; out bf16 or fp32 (F32OUT).
// 128x128 tile, BK=64 (half the barriers of BK=32), XOR-swizzled LDS
// (logical 16B chunk c of row r lives at slot c^(r&7)) -> <=2-way conflicts.
template <bool F32OUT>
__global__ __launch_bounds__(256) void gemm_bt(const u16* __restrict__ A,
                                               const u16* __restrict__ Bt,
                                               void* __restrict__ Cp,
                                               int M, int N, int K) {
  __shared__ __attribute__((aligned(16))) u16 Als[128 * 64];
  __shared__ __attribute__((aligned(16))) u16 Bls[128 * 64];
  const int tid = threadIdx.x;
  const int w = tid >> 6, lane = tid & 63, ln = lane & 15, quad = lane >> 4;
  const int m0 = blockIdx.y * 128, n0 = blockIdx.x * 128;
  const int moff = (w & 1) * 64, noff = (w >> 1) * 64;
  const f32x4 fzero = {0.f, 0.f, 0.f, 0.f};
  f32x4 acc[4][4];
#pragma unroll
  for (int i = 0; i < 4; i++)
#pragma unroll
    for (int j = 0; j < 4; j++) acc[i][j] = fzero;

  // staging source bases: 4 chunks each for A and B per thread
  const u16* aS[4];
  const u16* bS[4];
#pragma unroll
  for (int i = 0; i < 4; i++) {
    int s = i * 256 + tid;
    int row = s >> 3, cs = (s & 7) ^ (row & 7);
    aS[i] = A + (size_t)(m0 + row) * K + cs * 8;
    bS[i] = Bt + (size_t)(n0 + row) * K + cs * 8;
  }

  for (int k0 = 0; k0 < K; k0 += 64) {
    __syncthreads();
#pragma unroll
    for (int i = 0; i < 4; i++) {
      int s = i * 256 + tid;
      gl_lds16(aS[i] + k0, &Als[s * 8]);
      gl_lds16(bS[i] + k0, &Bls[s * 8]);
    }
    __syncthreads();
#pragma unroll
    for (int kk = 0; kk < 2; kk++) {
      bf16x8 af[4], bfv[4];
#pragma unroll
      for (int mi = 0; mi < 4; mi++)
        af[mi] = *(const bf16x8*)
            &Als[(moff + mi * 16 + ln) * 64 + (((kk * 4 + quad) ^ (ln & 7)) * 8)];
#pragma unroll
      for (int ni = 0; ni < 4; ni++)
        bfv[ni] = *(const bf16x8*)
            &Bls[(noff + ni * 16 + ln) * 64 + (((kk * 4 + quad) ^ (ln & 7)) * 8)];
#pragma unroll
      for (int mi = 0; mi < 4; mi++)
#pragma unroll
        for (int ni = 0; ni < 4; ni++)
          acc[mi][ni] = __builtin_amdgcn_mfma_f32_16x16x32_bf16(af[mi], bfv[ni],
                                                                acc[mi][ni], 0, 0, 0);
    }
  }
#pragma unroll
  for (int mi = 0; mi < 4; mi++)
#pragma unroll
    for (int ni = 0; ni < 4; ni++)
#pragma unroll
      for (int r = 0; r < 4; r++) {
        size_t m = m0 + moff + mi * 16 + quad * 4 + r;
        size_t n = n0 + noff + ni * 16 + ln;
        if (F32OUT)
          ((float*)Cp)[m * N + n] = acc[mi][ni][r];
        else
          ((u16*)Cp)[m * N + n] = f2bf(acc[mi][ni][r]);
      }
}

// ---------------------------------------------------------------------------
// Per-head LN of q and k slices of qkv[8192][1536] (bf16); fp32 params.
// Q pre-scaled by 0.125*log2(e): scores directly in exp2 domain (fixed-max
// softmax is safe: LN'd q,k => |score| <= ~11.5).
__global__ __launch_bounds__(256) void qk_ln(const u16* __restrict__ qkv,
                                             const float* __restrict__ qs,
                                             const float* __restrict__ qb,
                                             const float* __restrict__ ks,
                                             const float* __restrict__ kb,
                                             u16* __restrict__ Q,
                                             u16* __restrict__ Kb) {
  const float SCL = 0.18033688011112042f;  // 0.125 * log2(e)
  const int m = blockIdx.x;
  const int b = m >> 11, n = m & 2047;
  const int tid = threadIdx.x, w = tid >> 6, lane = tid & 63;
  const u16* rowp = qkv + (size_t)m * 1536;
  const float qsc = qs[lane], qbi = qb[lane];
  const float ksc = ks[lane], kbi = kb[lane];
#pragma unroll
  for (int i = 0; i < 4; i++) {
    int h = w * 4 + i;
    float v = bf2f(rowp[h * 64 + lane]);
    float s = v, q2 = v * v;
#pragma unroll
    for (int off = 1; off < 64; off <<= 1) {
      s += __shfl_xor(s, off);
      q2 += __shfl_xor(q2, off);
    }
    float mu = s * (1.0f / 64.0f);
    float var = q2 * (1.0f / 64.0f) - mu * mu;
    float y = ((v - mu) * rsqrtf(var + 1e-6f) * qsc + qbi) * SCL;
    Q[((size_t)(b * 16 + h) * 2048 + n) * 64 + lane] = f2bf(y);
  }
  {
    int g = w;
    float v = bf2f(rowp[1024 + g * 64 + lane]);
    float s = v, q2 = v * v;
#pragma unroll
    for (int off = 1; off < 64; off <<= 1) {
      s += __shfl_xor(s, off);
      q2 += __shfl_xor(q2, off);
    }
    float mu = s * (1.0f / 64.0f);
    float var = q2 * (1.0f / 64.0f) - mu * mu;
    float y = (v - mu) * rsqrtf(var + 1e-6f) * ksc + kbi;
    Kb[((size_t)(b * 4 + g) * 2048 + n) * 64 + lane] = f2bf(y);
  }
}

// ---------------------------------------------------------------------------
// V transpose: qkv v-slice -> Vt [b][g][64][2048]. grid = (32, 16).
// Round-2: keys are PERMUTED within each 64-key tile so attn's PV A-operand
// is one contiguous 16B chunk per lane:
//   key kappa = 32kc + quad*4 + u*16 + v  ->  pos p = 32kc + quad*8 + u*4 + v
// (kc=kappa>>5, quad=(kappa&15)>>2, u=(kappa>>4)&1, v=kappa&3).
__global__ __launch_bounds__(256) void vtrans(const u16* __restrict__ qkv,
                                              u16* __restrict__ Vt) {
  __shared__ __attribute__((aligned(16))) u16 t[64 * 72];
  const int n0 = blockIdx.x * 64;
  const int bg = blockIdx.y;
  const int b = bg >> 2, g = bg & 3;
  const int tid = threadIdx.x;
  const u16* src = qkv + (size_t)(b * 2048 + n0) * 1536 + 1280 + g * 64;
#pragma unroll
  for (int i = 0; i < 2; i++) {
    int c = i * 256 + tid;
    int row = c >> 3, cc = c & 7;
    *(f32x4*)&t[row * 72 + cc * 8] = *(const f32x4*)&src[(size_t)row * 1536 + cc * 8];
  }
  __syncthreads();
  u16* dst = Vt + (size_t)bg * 64 * 2048 + n0;
#pragma unroll
  for (int i = 0; i < 2; i++) {
    int c = i * 256 + tid;
    int d = c >> 3, nc = c & 7;
    // keys kappa = nc*8 + j; j=0..3 land at pA+j, j=4..7 at pA+8+(j&3)
    const int pA = 32 * (nc >> 2) + (nc & 1) * 16 + ((nc >> 1) & 1) * 4;
    u16x8 o;
#pragma unroll
    for (int j = 0; j < 8; j++) o[j] = t[(nc * 8 + j) * 72 + d];
    u16x4 lo = {o[0], o[1], o[2], o[3]};
    u16x4 hi = {o[4], o[5], o[6], o[7]};
    *(u16x4*)&dst[(size_t)d * 2048 + pA] = lo;
    *(u16x4*)&dst[(size_t)d * 2048 + pA + 8] = hi;
  }
}

// ---------------------------------------------------------------------------
// Flash attention, transposed-S, fixed-max softmax, KT=64 keys/iter.
// grid = (16, 64), block = 256 (4 waves x 32 q-rows).
//
// Round-2: P stays lane-local (round-1), but the PV A-operand (V) is now a
// SINGLE swizzled ds_read_b128 per (ni,kc) — the pre-permuted Vt layout (see
// vtrans) makes each lane's 8 PV keys one contiguous 16B chunk c=4kc+quad.
// This is byte-identical to the K read pattern, which measures ZERO bank
// conflicts; round-1's two b64 half-reads were 4 distinct rows per bank-pair
// (2x serialization, 8.4M conflict cycles — the whole counter).
// K/V double-buffered (32 KB LDS), one barrier per kt, prefetch before compute.
__global__ __launch_bounds__(256, 4) void attn(const u16* __restrict__ Q,
                                               const u16* __restrict__ Kb,
                                               const u16* __restrict__ Vt,
                                               u16* __restrict__ Out) {
  __shared__ __attribute__((aligned(16))) u16 Kls0[64 * 64];
  __shared__ __attribute__((aligned(16))) u16 Kls1[64 * 64];
  __shared__ __attribute__((aligned(16))) u16 Vls0[64 * 64];
  __shared__ __attribute__((aligned(16))) u16 Vls1[64 * 64];
  const int qt = blockIdx.x;
  const int bh = blockIdx.y;
  const int b = bh >> 4, h = bh & 15, g = h >> 2;
  const int tid = threadIdx.x, w = tid >> 6, lane = tid & 63;
  const int ln = lane & 15, quad = lane >> 4;
  const u16* Qg = Q + ((size_t)(b * 16 + h) * 2048 + qt * 128 + w * 32) * 64;
  const u16* Kg = Kb + (size_t)(b * 4 + g) * 2048 * 64;
  const u16* Vg = Vt + (size_t)(b * 4 + g) * 64 * 2048;
  const f32x4 fzero = {0.f, 0.f, 0.f, 0.f};

  // Q fragments (B-operand): rows m = mi*16+ln, k(d) = ks2*32 + quad*8
  bf16x8 qf[2][2];
#pragma unroll
  for (int mi = 0; mi < 2; mi++)
#pragma unroll
    for (int ks2 = 0; ks2 < 2; ks2++)
      qf[mi][ks2] = *(const bf16x8*)&Qg[(size_t)(mi * 16 + ln) * 64 + ks2 * 32 + quad * 8];

  f32x4 oacc[4][2];  // [ni(d-tile)][mi(m-tile)]
#pragma unroll
  for (int ni = 0; ni < 4; ni++)
#pragma unroll
    for (int mi = 0; mi < 2; mi++) oacc[ni][mi] = fzero;
  float lsum[2] = {0.f, 0.f};

  // staging geometry (constant per thread)
  const int sk0 = tid, sk1 = 256 + tid;
  const int krow0 = sk0 >> 3, kcs0 = (sk0 & 7) ^ (krow0 & 7);
  const int krow1 = sk1 >> 3, kcs1 = (sk1 & 7) ^ (krow1 & 7);

  auto STAGE = [&](int kt, u16* Kd, u16* Vd) {
    gl_lds16(Kg + (size_t)(kt * 64 + krow0) * 64 + kcs0 * 8, &Kd[sk0 * 8]);
    gl_lds16(Kg + (size_t)(kt * 64 + krow1) * 64 + kcs1 * 8, &Kd[sk1 * 8]);
    gl_lds16(Vg + (size_t)krow0 * 2048 + kt * 64 + kcs0 * 8, &Vd[sk0 * 8]);
    gl_lds16(Vg + (size_t)krow1 * 2048 + kt * 64 + kcs1 * 8, &Vd[sk1 * 8]);
  };

  auto BODY = [&](int kt, const u16* K_, const u16* V_, u16* Kn, u16* Vn) {
    if (kt + 1 < 32) STAGE(kt + 1, Kn, Vn);  // prefetch, in flight during compute

    // S^T: sacc[mi][ni][r] = S[key=ni*16+quad*4+r][m=mi*16+ln] (exp2 domain)
    f32x4 sacc[2][4];
#pragma unroll
    for (int ni = 0; ni < 4; ni++) {
      const int krow = ni * 16 + ln;
      bf16x8 kf0 = *(const bf16x8*)&K_[krow * 64 + ((quad ^ (ln & 7)) * 8)];
      bf16x8 kf1 = *(const bf16x8*)&K_[krow * 64 + (((4 + quad) ^ (ln & 7)) * 8)];
#pragma unroll
      for (int mi = 0; mi < 2; mi++) {
        f32x4 tt = __builtin_amdgcn_mfma_f32_16x16x32_bf16(kf0, qf[mi][0], fzero, 0, 0, 0);
        sacc[mi][ni] = __builtin_amdgcn_mfma_f32_16x16x32_bf16(kf1, qf[mi][1], tt, 0, 0, 0);
      }
    }

    // fixed-max softmax: p = exp2(s), packed straight into PV B-fragments.
    // pfa[mi][kc] element j: j<4 -> exp2(sacc[mi][2kc][j]); j>=4 -> exp2(sacc[mi][2kc+1][j-4])
    bf16x8 pfa[2][2];
#pragma unroll
    for (int mi = 0; mi < 2; mi++) {
      float ls = 0.f;
#pragma unroll
      for (int ni = 0; ni < 4; ni++) {
        float p0 = EXP2(sacc[mi][ni][0]);
        float p1 = EXP2(sacc[mi][ni][1]);
        float p2 = EXP2(sacc[mi][ni][2]);
        float p3 = EXP2(sacc[mi][ni][3]);
        ls += (p0 + p1) + (p2 + p3);
        const int e = (ni & 1) * 4;
        pfa[mi][ni >> 1][e + 0] = (__bf16)p0;
        pfa[mi][ni >> 1][e + 1] = (__bf16)p1;
        pfa[mi][ni >> 1][e + 2] = (__bf16)p2;
        pfa[mi][ni >> 1][e + 3] = (__bf16)p3;
      }
      ls += __shfl_xor(ls, 16);
      ls += __shfl_xor(ls, 32);
      lsum[mi] += ls;
    }

    // O^T += Vt * P^T. Key order of chunk c=4kc+quad in permuted-V:
    // element t -> key 32kc + quad*4 + (t>=4)*16 + (t&3), matching pfa.
#pragma unroll
    for (int kc = 0; kc < 2; kc++) {
#pragma unroll
      for (int ni = 0; ni < 4; ni++) {
        bf16x8 vf = *(const bf16x8*)
            &V_[(ni * 16 + ln) * 64 + (((4 * kc + quad) ^ (ln & 7)) * 8)];
#pragma unroll
        for (int mi = 0; mi < 2; mi++)
          oacc[ni][mi] = __builtin_amdgcn_mfma_f32_16x16x32_bf16(vf, pfa[mi][kc],
                                                                 oacc[ni][mi], 0, 0, 0);
      }
    }
    __syncthreads();  // drains prefetch vmcnt; all waves done reading K_/V_
  };

  STAGE(0, Kls0, Vls0);
  __syncthreads();
  for (int kt = 0; kt < 32; kt += 2) {
    BODY(kt, Kls0, Vls0, Kls1, Vls1);
    BODY(kt + 1, Kls1, Vls1, Kls0, Vls0);
  }

  // epilogue: O[m][d] = O^T / lsum; row n = qt*128 + w*32 + mi*16 + ln
#pragma unroll
  for (int mi = 0; mi < 2; mi++) {
    float inv = 1.0f / lsum[mi];
    u16* Og = Out + ((size_t)b * 2048 + qt * 128 + w * 32 + mi * 16 + ln) * 1024 + h * 64;
#pragma unroll
    for (int ni = 0; ni < 4; ni++) {
      bf16x4 ov = {(__bf16)(oacc[ni][mi][0] * inv), (__bf16)(oacc[ni][mi][1] * inv),
                   (__bf16)(oacc[ni][mi][2] * inv), (__bf16)(oacc[ni][mi][3] * inv)};
      *(bf16x4*)&Og[ni * 16 + quad * 4] = ov;
    }
  }
}

// ---------------------------------------------------------------------------
extern "C" void kernel_launch(void* const* d_in, const int* in_sizes, int n_in,
                              void* d_out, int out_size, void* d_ws, size_t ws_size,
                              hipStream_t stream) {
  const float* x    = (const float*)d_in[0];
  const float* lns  = (const float*)d_in[1];
  const float* lnb  = (const float*)d_in[2];
  const float* Wq   = (const float*)d_in[3];
  const float* Wkv  = (const float*)d_in[4];
  const float* qns  = (const float*)d_in[5];
  const float* qnb  = (const float*)d_in[6];
  const float* kns  = (const float*)d_in[7];
  const float* knb  = (const float*)d_in[8];
  const float* Wout = (const float*)d_in[9];
  float* out = (float*)d_out;
  char* ws = (char*)d_ws;

  const size_t o_xn  = 0;                 // 16 MB: xn (bf16), later Qbuf
  const size_t o_qkv = 16777216;          // 24 MB: qkv (bf16), later attn_out
  const size_t o_bt  = o_qkv + 25165824;  // 3 MB: W^T (bf16), reused for Wout^T
  const size_t o_k   = o_bt + 3145728;    // 4 MB: Kbuf
  const size_t o_vt  = o_k + 4194304;     // 4 MB: Vtbuf
  u16* xn   = (u16*)(ws + o_xn);
  u16* qkv  = (u16*)(ws + o_qkv);
  u16* bt   = (u16*)(ws + o_bt);
  u16* Kbuf = (u16*)(ws + o_k);
  u16* Vtb  = (u16*)(ws + o_vt);
  u16* Qbuf = xn;    // xn dead after GEMM1
  u16* aout = qkv;   // qkv dead after qk_ln/vtrans

  transpose64<<<dim3(16, 16), 256, 0, stream>>>(Wq, bt, 1024);
  transpose64<<<dim3(16, 8), 256, 0, stream>>>(Wkv, bt + 1024 * 1024, 512);
  ln_x<<<8192, 256, 0, stream>>>(x, lns, lnb, xn);
  gemm_bt<false><<<dim3(12, 64), 256, 0, stream>>>(xn, bt, qkv, 8192, 1536, 1024);
  transpose64<<<dim3(16, 16), 256, 0, stream>>>(Wout, bt, 1024);
  qk_ln<<<8192, 256, 0, stream>>>(qkv, qns, qnb, kns, knb, Qbuf, Kbuf);
  vtrans<<<dim3(32, 16), 256, 0, stream>>>(qkv, Vtb);
  attn<<<dim3(16, 64), 256, 0, stream>>>(Qbuf, Kbuf, Vtb, aout);
  gemm_bt<true><<<dim3(8, 64), 256, 0, stream>>>(aout, bt, out, 8192, 1024, 1024);

  (void)in_sizes; (void)n_in; (void)out_size; (void)ws_size;
}

// Round 3
// 272.307 us; speedup vs baseline: 1.0714x; 1.0150x over previous
//
#include <hip/hip_runtime.h>
#include <cstdint>
#include <cstddef>

// All external tensors are FP32 (per reference). Internals use bf16 for MFMA.
typedef unsigned short u16;
typedef __attribute__((ext_vector_type(4))) float f32x4;
typedef __attribute__((ext_vector_type(8))) __bf16 bf16x8;
typedef __attribute__((ext_vector_type(4))) __bf16 bf16x4;
typedef __attribute__((ext_vector_type(8))) unsigned short u16x8;
typedef __attribute__((ext_vector_type(4))) unsigned short u16x4;

#define DEV static __device__ __forceinline__

#if __has_builtin(__builtin_amdgcn_exp2f)
#define EXP2(x) __builtin_amdgcn_exp2f(x)
#else
#define EXP2(x) exp2f(x)
#endif

DEV float bf2f(u16 v) { return __uint_as_float(((unsigned)v) << 16); }
DEV u16 f2bf(float f) {
  unsigned u = __float_as_uint(f);
  return (u16)((u + 0x7FFFu + ((u >> 16) & 1u)) >> 16);
}

DEV void gl_lds16(const void* g, void* l) {
  __builtin_amdgcn_global_load_lds((const __attribute__((address_space(1))) void*)g,
                                   (__attribute__((address_space(3))) void*)l, 16, 0, 0);
}

// ---------------------------------------------------------------------------
// 64x64 tiled transpose + fp32->bf16 cast: out[c][r] = bf16(in[r][c]).
__global__ __launch_bounds__(256) void transpose64(const float* __restrict__ in,
                                                   u16* __restrict__ out, int incols) {
  __shared__ __attribute__((aligned(16))) u16 t[64 * 72];
  const int r0 = blockIdx.x * 64, c0 = blockIdx.y * 64, tid = threadIdx.x;
#pragma unroll
  for (int i = 0; i < 2; i++) {
    int c = i * 256 + tid;
    int row = c >> 3, cc = c & 7;
    const float* src = &in[(size_t)(r0 + row) * incols + c0 + cc * 8];
    f32x4 v0 = *(const f32x4*)src;
    f32x4 v1 = *(const f32x4*)(src + 4);
    u16x8 o;
#pragma unroll
    for (int j = 0; j < 4; j++) { o[j] = f2bf(v0[j]); o[4 + j] = f2bf(v1[j]); }
    *(u16x8*)&t[row * 72 + cc * 8] = o;
  }
  __syncthreads();
#pragma unroll
  for (int i = 0; i < 2; i++) {
    int c = i * 256 + tid;
    int d = c >> 3, nc = c & 7;
    u16x8 o;
#pragma unroll
    for (int j = 0; j < 8; j++) o[j] = t[(nc * 8 + j) * 72 + d];
    *(u16x8*)&out[(size_t)(c0 + d) * 1024 + r0 + nc * 8] = o;
  }
}

// ---------------------------------------------------------------------------
// LayerNorm over DIM=1024 (fp32 in, bf16 out), one block per row.
__global__ __launch_bounds__(256) void ln_x(const float* __restrict__ x,
                                            const float* __restrict__ sc,
                                            const float* __restrict__ bi,
                                            u16* __restrict__ xn) {
  __shared__ float red[8];
  const int row = blockIdx.x, tid = threadIdx.x;
  const int w = tid >> 6;
  f32x4 f = *(const f32x4*)&x[(size_t)row * 1024 + tid * 4];
  float s = f[0] + f[1] + f[2] + f[3];
  float q = f[0] * f[0] + f[1] * f[1] + f[2] * f[2] + f[3] * f[3];
#pragma unroll
  for (int off = 1; off < 64; off <<= 1) {
    s += __shfl_xor(s, off);
    q += __shfl_xor(q, off);
  }
  if ((tid & 63) == 0) { red[w] = s; red[4 + w] = q; }
  __syncthreads();
  float S = red[0] + red[1] + red[2] + red[3];
  float Q = red[4] + red[5] + red[6] + red[7];
  float mu = S * (1.0f / 1024.0f);
  float var = Q * (1.0f / 1024.0f) - mu * mu;
  float rs = rsqrtf(var + 1e-6f);
  f32x4 scv = *(const f32x4*)&sc[tid * 4];
  f32x4 biv = *(const f32x4*)&bi[tid * 4];
  u16* o = xn + (size_t)row * 1024 + tid * 4;
#pragma unroll
  for (int j = 0; j < 4; j++) o[j] = f2bf((f[j] - mu) * rs * scv[j] + biv[j]);
}

// ---------------------------------------------------------------------------
// C[M][N] = A[M][K] * Bt[N][K]^T, bf16 in; out bf16 or fp32 (F32OUT).
// 128x128 tile, BK=64 (half the barriers of BK=32), XOR-swizzled LDS
// (logical 16B chunk c of row r lives at slot c^(r&7)) -> <=2-way conflicts.
template <bool F32OUT>
__global__ __launch_bounds__(256) void gemm_bt(const u16* __restrict__ A,
                                               const u16* __restrict__ Bt,
                                               void* __restrict__ Cp,
                                               int M, int N, int K) {
  __shared__ __attribute__((aligned(16))) u16 Als[128 * 64];
  __shared__ __attribute__((aligned(16))) u16 Bls[128 * 64];
  const int tid = threadIdx.x;
  const int w = tid >> 6, lane = tid & 63, ln = lane & 15, quad = lane >> 4;
  const int m0 = blockIdx.y * 128, n0 = blockIdx.x * 128;
  const int moff = (w & 1) * 64, noff = (w >> 1) * 64;
  const f32x4 fzero = {0.f, 0.f, 0.f, 0.f};
  f32x4 acc[4][4];
#pragma unroll
  for (int i = 0; i < 4; i++)
#pragma unroll
    for (int j = 0; j < 4; j++) acc[i][j] = fzero;

  // staging source bases: 4 chunks each for A and B per thread
  const u16* aS[4];
  const u16* bS[4];
#pragma unroll
  for (int i = 0; i < 4; i++) {
    int s = i * 256 + tid;
    int row = s >> 3, cs = (s & 7) ^ (row & 7);
    aS[i] = A + (size_t)(m0 + row) * K + cs * 8;
    bS[i] = Bt + (size_t)(n0 + row) * K + cs * 8;
  }

  for (int k0 = 0; k0 < K; k0 += 64) {
    __syncthreads();
#pragma unroll
    for (int i = 0; i < 4; i++) {
      int s = i * 256 + tid;
      gl_lds16(aS[i] + k0, &Als[s * 8]);
      gl_lds16(bS[i] + k0, &Bls[s * 8]);
    }
    __syncthreads();
#pragma unroll
    for (int kk = 0; kk < 2; kk++) {
      bf16x8 af[4], bfv[4];
#pragma unroll
      for (int mi = 0; mi < 4; mi++)
        af[mi] = *(const bf16x8*)
            &Als[(moff + mi * 16 + ln) * 64 + (((kk * 4 + quad) ^ (ln & 7)) * 8)];
#pragma unroll
      for (int ni = 0; ni < 4; ni++)
        bfv[ni] = *(const bf16x8*)
            &Bls[(noff + ni * 16 + ln) * 64 + (((kk * 4 + quad) ^ (ln & 7)) * 8)];
#pragma unroll
      for (int mi = 0; mi < 4; mi++)
#pragma unroll
        for (int ni = 0; ni < 4; ni++)
          acc[mi][ni] = __builtin_amdgcn_mfma_f32_16x16x32_bf16(af[mi], bfv[ni],
                                                                acc[mi][ni], 0, 0, 0);
    }
  }
#pragma unroll
  for (int mi = 0; mi < 4; mi++)
#pragma unroll
    for (int ni = 0; ni < 4; ni++)
#pragma unroll
      for (int r = 0; r < 4; r++) {
        size_t m = m0 + moff + mi * 16 + quad * 4 + r;
        size_t n = n0 + noff + ni * 16 + ln;
        if (F32OUT)
          ((float*)Cp)[m * N + n] = acc[mi][ni][r];
        else
          ((u16*)Cp)[m * N + n] = f2bf(acc[mi][ni][r]);
      }
}

// ---------------------------------------------------------------------------
// Per-head LN of q and k slices of qkv[8192][1536] (bf16); fp32 params.
// Q pre-scaled by 0.125*log2(e): scores directly in exp2 domain (fixed-max
// softmax is safe: LN'd q,k => |score| <= ~11.5).
__global__ __launch_bounds__(256) void qk_ln(const u16* __restrict__ qkv,
                                             const float* __restrict__ qs,
                                             const float* __restrict__ qb,
                                             const float* __restrict__ ks,
                                             const float* __restrict__ kb,
                                             u16* __restrict__ Q,
                                             u16* __restrict__ Kb) {
  const float SCL = 0.18033688011112042f;  // 0.125 * log2(e)
  const int m = blockIdx.x;
  const int b = m >> 11, n = m & 2047;
  const int tid = threadIdx.x, w = tid >> 6, lane = tid & 63;
  const u16* rowp = qkv + (size_t)m * 1536;
  const float qsc = qs[lane], qbi = qb[lane];
  const float ksc = ks[lane], kbi = kb[lane];
#pragma unroll
  for (int i = 0; i < 4; i++) {
    int h = w * 4 + i;
    float v = bf2f(rowp[h * 64 + lane]);
    float s = v, q2 = v * v;
#pragma unroll
    for (int off = 1; off < 64; off <<= 1) {
      s += __shfl_xor(s, off);
      q2 += __shfl_xor(q2, off);
    }
    float mu = s * (1.0f / 64.0f);
    float var = q2 * (1.0f / 64.0f) - mu * mu;
    float y = ((v - mu) * rsqrtf(var + 1e-6f) * qsc + qbi) * SCL;
    Q[((size_t)(b * 16 + h) * 2048 + n) * 64 + lane] = f2bf(y);
  }
  {
    int g = w;
    float v = bf2f(rowp[1024 + g * 64 + lane]);
    float s = v, q2 = v * v;
#pragma unroll
    for (int off = 1; off < 64; off <<= 1) {
      s += __shfl_xor(s, off);
      q2 += __shfl_xor(q2, off);
    }
    float mu = s * (1.0f / 64.0f);
    float var = q2 * (1.0f / 64.0f) - mu * mu;
    float y = (v - mu) * rsqrtf(var + 1e-6f) * ksc + kbi;
    Kb[((size_t)(b * 4 + g) * 2048 + n) * 64 + lane] = f2bf(y);
  }
}

// ---------------------------------------------------------------------------
// V transpose: qkv v-slice -> Vt [b][g][64][2048]. grid = (32, 16).
// Keys are PERMUTED within each 64-key tile so attn's PV A-operand is one
// contiguous 16B chunk per lane:
//   key kappa = 32c + quad*4 + u*16 + v  ->  pos p = 32c + quad*8 + u*4 + v
__global__ __launch_bounds__(256) void vtrans(const u16* __restrict__ qkv,
                                              u16* __restrict__ Vt) {
  __shared__ __attribute__((aligned(16))) u16 t[64 * 72];
  const int n0 = blockIdx.x * 64;
  const int bg = blockIdx.y;
  const int b = bg >> 2, g = bg & 3;
  const int tid = threadIdx.x;
  const u16* src = qkv + (size_t)(b * 2048 + n0) * 1536 + 1280 + g * 64;
#pragma unroll
  for (int i = 0; i < 2; i++) {
    int c = i * 256 + tid;
    int row = c >> 3, cc = c & 7;
    *(f32x4*)&t[row * 72 + cc * 8] = *(const f32x4*)&src[(size_t)row * 1536 + cc * 8];
  }
  __syncthreads();
  u16* dst = Vt + (size_t)bg * 64 * 2048 + n0;
#pragma unroll
  for (int i = 0; i < 2; i++) {
    int c = i * 256 + tid;
    int d = c >> 3, nc = c & 7;
    // keys kappa = nc*8 + j; j=0..3 land at pA+j, j=4..7 at pA+8+(j&3)
    const int pA = 32 * (nc >> 2) + (nc & 1) * 16 + ((nc >> 1) & 1) * 4;
    u16x8 o;
#pragma unroll
    for (int j = 0; j < 8; j++) o[j] = t[(nc * 8 + j) * 72 + d];
    u16x4 lo = {o[0], o[1], o[2], o[3]};
    u16x4 hi = {o[4], o[5], o[6], o[7]};
    *(u16x4*)&dst[(size_t)d * 2048 + pA] = lo;
    *(u16x4*)&dst[(size_t)d * 2048 + pA + 8] = hi;
  }
}

// ---------------------------------------------------------------------------
// Flash attention, transposed-S, fixed-max softmax, KT=64 keys/iter.
//
// Round-3: 64 q-rows per wave (was 32), 2 waves per block (128 threads),
// block still covers 128 rows -> grid (16,64) unchanged, 4 blocks/CU.
// Rationale: each wave must read the FULL 8KB K + 8KB V tile from LDS per
// iteration regardless of its q-row count; LDS reads were the top pipe
// (~3600 cyc/CU/iter of the 6768 total). Doubling rows/wave halves total
// LDS read traffic per CU (8 waves x 16 b128 instead of 16 x 16).
// Keys processed in two 32-key chunks to keep sacc at 32 VGPRs.
// lsum cross-lane reduction deferred to the epilogue (per-lane accumulate),
// removing the per-iteration shuffles from the DS pipe. s_setprio(1) around
// MFMA clusters (independent blocks/CU -> scheduler has roles to arbitrate).
__global__ __launch_bounds__(128, 2) void attn(const u16* __restrict__ Q,
                                               const u16* __restrict__ Kb,
                                               const u16* __restrict__ Vt,
                                               u16* __restrict__ Out) {
  __shared__ __attribute__((aligned(16))) u16 Kls0[64 * 64];
  __shared__ __attribute__((aligned(16))) u16 Kls1[64 * 64];
  __shared__ __attribute__((aligned(16))) u16 Vls0[64 * 64];
  __shared__ __attribute__((aligned(16))) u16 Vls1[64 * 64];
  const int qt = blockIdx.x;
  const int bh = blockIdx.y;
  const int b = bh >> 4, h = bh & 15, g = h >> 2;
  const int tid = threadIdx.x, w = tid >> 6, lane = tid & 63;
  const int ln = lane & 15, quad = lane >> 4;
  const u16* Qg = Q + ((size_t)(b * 16 + h) * 2048 + qt * 128 + w * 64) * 64;
  const u16* Kg = Kb + (size_t)(b * 4 + g) * 2048 * 64;
  const u16* Vg = Vt + (size_t)(b * 4 + g) * 64 * 2048;
  const f32x4 fzero = {0.f, 0.f, 0.f, 0.f};

  // Q fragments (B-operand): rows m = mi*16+ln, k(d) = ks2*32 + quad*8
  bf16x8 qf[4][2];
#pragma unroll
  for (int mi = 0; mi < 4; mi++)
#pragma unroll
    for (int ks2 = 0; ks2 < 2; ks2++)
      qf[mi][ks2] = *(const bf16x8*)&Qg[(size_t)(mi * 16 + ln) * 64 + ks2 * 32 + quad * 8];

  f32x4 oacc[4][4];  // [ni(d-tile)][mi(m-tile)]
#pragma unroll
  for (int ni = 0; ni < 4; ni++)
#pragma unroll
    for (int mi = 0; mi < 4; mi++) oacc[ni][mi] = fzero;
  float lacc[4] = {0.f, 0.f, 0.f, 0.f};  // per-lane partial row sums

  // staging geometry: 4 K-chunks + 4 V-chunks per thread (128 threads)
  int krow[4], kcs[4];
#pragma unroll
  for (int i = 0; i < 4; i++) {
    int s = i * 128 + tid;
    krow[i] = s >> 3;
    kcs[i] = (s & 7) ^ (krow[i] & 7);
  }

  auto STAGE = [&](int kt, u16* Kd, u16* Vd) {
#pragma unroll
    for (int i = 0; i < 4; i++) {
      int s = i * 128 + tid;
      gl_lds16(Kg + (size_t)(kt * 64 + krow[i]) * 64 + kcs[i] * 8, &Kd[s * 8]);
      gl_lds16(Vg + (size_t)krow[i] * 2048 + kt * 64 + kcs[i] * 8, &Vd[s * 8]);
    }
  };

  auto BODY = [&](int kt, const u16* K_, const u16* V_, u16* Kn, u16* Vn) {
    if (kt + 1 < 32) STAGE(kt + 1, Kn, Vn);  // prefetch, in flight during compute

#pragma unroll
    for (int c = 0; c < 2; c++) {  // two 32-key chunks
      // K fragments for keys c*32 + [0,32)
      bf16x8 kf[2][2];  // [ni(key-16-tile)][kstep(d half)]
#pragma unroll
      for (int ni = 0; ni < 2; ni++) {
        const int kr = (c * 32 + ni * 16 + ln) * 64;
        kf[ni][0] = *(const bf16x8*)&K_[kr + ((quad ^ (ln & 7)) * 8)];
        kf[ni][1] = *(const bf16x8*)&K_[kr + (((4 + quad) ^ (ln & 7)) * 8)];
      }

      // S^T: sacc[mi][ni][r] = S[key=c*32+ni*16+quad*4+r][m=mi*16+ln]
      f32x4 sacc[4][2];
      __builtin_amdgcn_s_setprio(1);
#pragma unroll
      for (int ni = 0; ni < 2; ni++)
#pragma unroll
        for (int mi = 0; mi < 4; mi++) {
          f32x4 tt = __builtin_amdgcn_mfma_f32_16x16x32_bf16(kf[ni][0], qf[mi][0],
                                                             fzero, 0, 0, 0);
          sacc[mi][ni] = __builtin_amdgcn_mfma_f32_16x16x32_bf16(kf[ni][1], qf[mi][1],
                                                                 tt, 0, 0, 0);
        }
      __builtin_amdgcn_s_setprio(0);

      // fixed-max softmax: p = exp2(s), packed straight into PV B-fragments.
      // pfa[mi][j]: j<4 -> exp2(sacc[mi][0][j]); j>=4 -> exp2(sacc[mi][1][j-4])
      bf16x8 pfa[4];
#pragma unroll
      for (int mi = 0; mi < 4; mi++) {
        float p0 = EXP2(sacc[mi][0][0]);
        float p1 = EXP2(sacc[mi][0][1]);
        float p2 = EXP2(sacc[mi][0][2]);
        float p3 = EXP2(sacc[mi][0][3]);
        float p4 = EXP2(sacc[mi][1][0]);
        float p5 = EXP2(sacc[mi][1][1]);
        float p6 = EXP2(sacc[mi][1][2]);
        float p7 = EXP2(sacc[mi][1][3]);
        lacc[mi] += ((p0 + p1) + (p2 + p3)) + ((p4 + p5) + (p6 + p7));
        pfa[mi][0] = (__bf16)p0; pfa[mi][1] = (__bf16)p1;
        pfa[mi][2] = (__bf16)p2; pfa[mi][3] = (__bf16)p3;
        pfa[mi][4] = (__bf16)p4; pfa[mi][5] = (__bf16)p5;
        pfa[mi][6] = (__bf16)p6; pfa[mi][7] = (__bf16)p7;
      }

      // O^T += Vt * P^T. Permuted-V chunk c*4+quad holds this lane's 8 keys
      // in exactly pfa's order.
#pragma unroll
      for (int ni = 0; ni < 4; ni++) {
        bf16x8 vf = *(const bf16x8*)
            &V_[(ni * 16 + ln) * 64 + (((4 * c + quad) ^ (ln & 7)) * 8)];
        __builtin_amdgcn_s_setprio(1);
#pragma unroll
        for (int mi = 0; mi < 4; mi++)
          oacc[ni][mi] = __builtin_amdgcn_mfma_f32_16x16x32_bf16(vf, pfa[mi],
                                                                 oacc[ni][mi], 0, 0, 0);
        __builtin_amdgcn_s_setprio(0);
      }
    }
    __syncthreads();  // drains prefetch vmcnt; all waves done reading K_/V_
  };

  STAGE(0, Kls0, Vls0);
  __syncthreads();
  for (int kt = 0; kt < 32; kt += 2) {
    BODY(kt, Kls0, Vls0, Kls1, Vls1);
    BODY(kt + 1, Kls1, Vls1, Kls0, Vls0);
  }

  // epilogue: reduce row sums across quads, then O[m][d] = O^T / lsum
#pragma unroll
  for (int mi = 0; mi < 4; mi++) {
    float ls = lacc[mi];
    ls += __shfl_xor(ls, 16);
    ls += __shfl_xor(ls, 32);
    float inv = 1.0f / ls;
    u16* Og = Out + ((size_t)b * 2048 + qt * 128 + w * 64 + mi * 16 + ln) * 1024 + h * 64;
#pragma unroll
    for (int ni = 0; ni < 4; ni++) {
      bf16x4 ov = {(__bf16)(oacc[ni][mi][0] * inv), (__bf16)(oacc[ni][mi][1] * inv),
                   (__bf16)(oacc[ni][mi][2] * inv), (__bf16)(oacc[ni][mi][3] * inv)};
      *(bf16x4*)&Og[ni * 16 + quad * 4] = ov;
    }
  }
}

// ---------------------------------------------------------------------------
extern "C" void kernel_launch(void* const* d_in, const int* in_sizes, int n_in,
                              void* d_out, int out_size, void* d_ws, size_t ws_size,
                              hipStream_t stream) {
  const float* x    = (const float*)d_in[0];
  const float* lns  = (const float*)d_in[1];
  const float* lnb  = (const float*)d_in[2];
  const float* Wq   = (const float*)d_in[3];
  const float* Wkv  = (const float*)d_in[4];
  const float* qns  = (const float*)d_in[5];
  const float* qnb  = (const float*)d_in[6];
  const float* kns  = (const float*)d_in[7];
  const float* knb  = (const float*)d_in[8];
  const float* Wout = (const float*)d_in[9];
  float* out = (float*)d_out;
  char* ws = (char*)d_ws;

  const size_t o_xn  = 0;                 // 16 MB: xn (bf16), later Qbuf
  const size_t o_qkv = 16777216;          // 24 MB: qkv (bf16), later attn_out
  const size_t o_bt  = o_qkv + 25165824;  // 3 MB: W^T (bf16), reused for Wout^T
  const size_t o_k   = o_bt + 3145728;    // 4 MB: Kbuf
  const size_t o_vt  = o_k + 4194304;     // 4 MB: Vtbuf
  u16* xn   = (u16*)(ws + o_xn);
  u16* qkv  = (u16*)(ws + o_qkv);
  u16* bt   = (u16*)(ws + o_bt);
  u16* Kbuf = (u16*)(ws + o_k);
  u16* Vtb  = (u16*)(ws + o_vt);
  u16* Qbuf = xn;    // xn dead after GEMM1
  u16* aout = qkv;   // qkv dead after qk_ln/vtrans

  transpose64<<<dim3(16, 16), 256, 0, stream>>>(Wq, bt, 1024);
  transpose64<<<dim3(16, 8), 256, 0, stream>>>(Wkv, bt + 1024 * 1024, 512);
  ln_x<<<8192, 256, 0, stream>>>(x, lns, lnb, xn);
  gemm_bt<false><<<dim3(12, 64), 256, 0, stream>>>(xn, bt, qkv, 8192, 1536, 1024);
  transpose64<<<dim3(16, 16), 256, 0, stream>>>(Wout, bt, 1024);
  qk_ln<<<8192, 256, 0, stream>>>(qkv, qns, qnb, kns, knb, Qbuf, Kbuf);
  vtrans<<<dim3(32, 16), 256, 0, stream>>>(qkv, Vtb);
  attn<<<dim3(16, 64), 128, 0, stream>>>(Qbuf, Kbuf, Vtb, aout);
  gemm_bt<true><<<dim3(8, 64), 256, 0, stream>>>(aout, bt, out, 8192, 1024, 1024);

  (void)in_sizes; (void)n_in; (void)out_size; (void)ws_size;
}